// Round 14
// baseline (128.881 us; speedup 1.0000x reference)
//
#include <hip/hip_runtime.h>
#include <hip/hip_fp16.h>

#define N_NODES 50000
#define N_EDGES 800000
#define D 64
#define NBUCK 196                 // ceil(N_NODES / 256)
#define BUCK_SHIFT 8
#define PA_CHUNK 2048
#define PA_BLOCKS ((N_EDGES + PA_CHUNK - 1) / PA_CHUNK)   // 391
#define PB_CAP 8192               // Poisson(4082) never reaches this; fallback kept anyway
#define PULL_GRID 2048            // 8 blocks/CU, grid-stride over nodes

typedef float fx4 __attribute__((ext_vector_type(4)));   // native vec for nontemporal builtins

// ---- tiny init -------------------------------------------------------------
__global__ void zero_bhist(int* __restrict__ bhist) {
    int t = threadIdx.x;
    if (t < NBUCK) bhist[t] = 0;
}

// ---- coarse 196-bucket histogram of dst (LDS-privatized) -------------------
__global__ __launch_bounds__(256) void bucket_hist(const int* __restrict__ dst,
                                                   int* __restrict__ bhist) {
    __shared__ int h[NBUCK];
    for (int i = threadIdx.x; i < NBUCK; i += 256) h[i] = 0;
    __syncthreads();
    int stride = gridDim.x * 256;
    for (int e = blockIdx.x * 256 + threadIdx.x; e < N_EDGES; e += stride)
        atomicAdd(&h[dst[e] >> BUCK_SHIFT], 1);
    __syncthreads();
    for (int i = threadIdx.x; i < NBUCK; i += 256)
        if (h[i]) atomicAdd(&bhist[i], h[i]);
}

// ---- 1-block scan of 196 bucket counts -> bucketoff / bnext ---------------
__global__ __launch_bounds__(256) void bucket_scan(const int* __restrict__ bhist,
                                                   int* __restrict__ bucketoff,
                                                   int* __restrict__ bnext,
                                                   int* __restrict__ rowptr) {
    __shared__ int lds[256];
    int t = threadIdx.x;
    int v = (t < NBUCK) ? bhist[t] : 0;
    lds[t] = v;
    __syncthreads();
    for (int off = 1; off < 256; off <<= 1) {
        int u = (t >= off) ? lds[t - off] : 0;
        __syncthreads();
        lds[t] += u;
        __syncthreads();
    }
    if (t < NBUCK) { bucketoff[t] = lds[t] - v; bnext[t] = lds[t] - v; }
    if (t == 0)    { bucketoff[NBUCK] = N_EDGES; rowptr[N_NODES] = N_EDGES; }
}

// ---- pass A: bin edges by dst>>8 into tmp regions (block-privatized) -------
__global__ __launch_bounds__(256) void pass_a(const int* __restrict__ src,
                                              const int* __restrict__ dst,
                                              int* __restrict__ bnext,
                                              unsigned int* __restrict__ tmp) {
    __shared__ int cnt[NBUCK], loc[NBUCK], cur[NBUCK], gbase[NBUCK];
    __shared__ int s[256];
    __shared__ unsigned int stage[PA_CHUNK];
    __shared__ unsigned char sb[PA_CHUNK];
    int t = threadIdx.x;
    int base = blockIdx.x * PA_CHUNK;
    int len = N_EDGES - base; if (len > PA_CHUNK) len = PA_CHUNK;

    for (int i = t; i < NBUCK; i += 256) cnt[i] = 0;
    __syncthreads();
    for (int j = t; j < len; j += 256)
        atomicAdd(&cnt[dst[base + j] >> BUCK_SHIFT], 1);
    __syncthreads();
    int v = (t < NBUCK) ? cnt[t] : 0;
    s[t] = v;
    __syncthreads();
    for (int off = 1; off < 256; off <<= 1) {
        int u = (t >= off) ? s[t - off] : 0;
        __syncthreads();
        s[t] += u;
        __syncthreads();
    }
    if (t < NBUCK) {
        loc[t] = s[t] - v;
        cur[t] = s[t] - v;
        gbase[t] = v ? atomicAdd(&bnext[t], v) : 0;
    }
    __syncthreads();
    for (int j = t; j < len; j += 256) {
        int d = dst[base + j], s0 = src[base + j];
        int b = d >> BUCK_SHIFT;
        int r = atomicAdd(&cur[b], 1);
        stage[r] = ((unsigned)d << 16) | (unsigned)s0;
        sb[r] = (unsigned char)b;
    }
    __syncthreads();
    for (int j = t; j < len; j += 256) {
        int b = sb[j];
        tmp[gbase[b] + (j - loc[b])] = stage[j];
    }
}

// ---- pass B: per-bucket counting sort -> csr_src, rowptr, dinv, rsq; also
// writes y0 rows for its 256-node range (fused former scale_kernel) ---------
__global__ __launch_bounds__(256) void pass_b(const unsigned int* __restrict__ tmp,
                                              const int* __restrict__ bucketoff,
                                              int* __restrict__ rowptr,
                                              float* __restrict__ dinv,
                                              float* __restrict__ rsq,
                                              unsigned short* __restrict__ csr_src,
                                              const float* __restrict__ emb,
                                              __half* __restrict__ y0) {
    __shared__ int hist[256], ptr[256], cur[256];
    __shared__ float sdinv[256];
    __shared__ unsigned int in[PB_CAP];
    __shared__ unsigned short outs[PB_CAP];
    int b = blockIdx.x, t = threadIdx.x;
    int base = bucketoff[b], end = bucketoff[b + 1];
    int k = end - base;
    int node0 = b << BUCK_SHIFT;
    int nloc = N_NODES - node0; if (nloc > 256) nloc = 256;

    hist[t] = 0;
    __syncthreads();
    bool fits = (k <= PB_CAP);
    for (int j = t; j < k; j += 256) {
        unsigned int w = tmp[base + j];
        if (fits) in[j] = w;
        atomicAdd(&hist[(w >> 16) & 255], 1);
    }
    __syncthreads();
    int v = hist[t];
    ptr[t] = v;
    __syncthreads();
    for (int off = 1; off < 256; off <<= 1) {
        int u = (t >= off) ? ptr[t - off] : 0;
        __syncthreads();
        ptr[t] += u;
        __syncthreads();
    }
    int excl = ptr[t] - v;
    cur[t] = excl;
    if (t < nloc) {
        float dn = v > 0 ? rsqrtf((float)v) : 0.0f;
        rowptr[node0 + t] = base + excl;
        dinv[node0 + t] = dn;
        rsq[node0 + t]  = sqrtf((float)v);
        sdinv[t] = dn;
    }
    __syncthreads();
    if (fits) {
        for (int j = t; j < k; j += 256) {
            unsigned int w = in[j];
            int r = atomicAdd(&cur[(w >> 16) & 255], 1);
            outs[r] = (unsigned short)(w & 0xFFFF);
        }
        __syncthreads();
        for (int j = t; j < k; j += 256) csr_src[base + j] = outs[j];
    } else {
        for (int j = t; j < k; j += 256) {
            unsigned int w = tmp[base + j];
            int r = atomicAdd(&cur[(w >> 16) & 255], 1);
            csr_src[base + r] = (unsigned short)(w & 0xFFFF);
        }
    }

    // fused scale: y0[n,:] = dinv[n] * emb[n,:] for this bucket's nodes
    int nv = nloc * 8;                    // uint4 stores (8 fp16 each)
    for (int q = t; q < nv; q += 256) {
        int n   = q >> 3;
        int off = (q & 7) * 8;
        float s = sdinv[n];
        const float* ep = emb + (size_t)(node0 + n) * D + off;
        float4 a = *(const float4*)ep;
        float4 bb = *(const float4*)(ep + 4);
        __half2 h[4];
        h[0] = __floats2half2_rn(a.x * s, a.y * s);
        h[1] = __floats2half2_rn(a.z * s, a.w * s);
        h[2] = __floats2half2_rn(bb.x * s, bb.y * s);
        h[3] = __floats2half2_rn(bb.z * s, bb.w * s);
        *(uint4*)(y0 + (size_t)(node0 + n) * D + off) = *(const uint4*)h;
    }
}

// ---- pull: grid-stride, one wave per dst node; 8 groups x 8 dims -----------
// One VMEM instr fetches 8 full 128B rows. FINAL=0: y_out = dinv^2 * acc.
// FINAL=1: x3 = dinv*acc; out = 0.25*(emb + rsq*(y1+y2) + x3)
// FINAL=1 epilogue uses nontemporal emb loads / out stores to keep L2 for y.
template <int FINAL>
__global__ __launch_bounds__(256) void pull_kernel(
        const int* __restrict__ rowptr, const unsigned short* __restrict__ csr_src,
        const float* __restrict__ dinv, const __half* __restrict__ y,
        __half* __restrict__ y_out,
        const float* __restrict__ rsq, const __half* __restrict__ y1,
        const __half* __restrict__ y2, const float* __restrict__ emb,
        float* __restrict__ out) {
    int lane = threadIdx.x & 63;
    int g  = lane >> 3;     // group 0..7 (edge slot within chunk)
    int gl = lane & 7;      // lane in group (dim block)
    int node0 = blockIdx.x * 4 + (threadIdx.x >> 6);

    for (int node = node0; node < N_NODES; node += PULL_GRID * 4) {
        int beg = rowptr[node];
        int end = rowptr[node + 1];

        float acc0 = 0.f, acc1 = 0.f, acc2 = 0.f, acc3 = 0.f;
        float acc4 = 0.f, acc5 = 0.f, acc6 = 0.f, acc7 = 0.f;

        for (int e0 = beg; e0 < end; e0 += 64) {
            int kk = end - e0; if (kk > 64) kk = 64;
            int idxv = (e0 + lane < end) ? (int)csr_src[e0 + lane] : 0;
            int nch = (kk + 7) >> 3;
            for (int i = 0; i < nch; ++i) {
                int pos = 8 * i + g;
                int s = __shfl(idxv, pos, 64);
                if (pos < kk) {
                    const uint4* p = (const uint4*)(y + (size_t)s * D + gl * 8);
                    uint4 v = *p;
                    const __half2* h = (const __half2*)&v;
                    float2 f0 = __half22float2(h[0]);
                    float2 f1 = __half22float2(h[1]);
                    float2 f2 = __half22float2(h[2]);
                    float2 f3 = __half22float2(h[3]);
                    acc0 += f0.x; acc1 += f0.y; acc2 += f1.x; acc3 += f1.y;
                    acc4 += f2.x; acc5 += f2.y; acc6 += f3.x; acc7 += f3.y;
                }
            }
        }

        #pragma unroll
        for (int off = 8; off < 64; off <<= 1) {
            acc0 += __shfl_xor(acc0, off, 64);
            acc1 += __shfl_xor(acc1, off, 64);
            acc2 += __shfl_xor(acc2, off, 64);
            acc3 += __shfl_xor(acc3, off, 64);
            acc4 += __shfl_xor(acc4, off, 64);
            acc5 += __shfl_xor(acc5, off, 64);
            acc6 += __shfl_xor(acc6, off, 64);
            acc7 += __shfl_xor(acc7, off, 64);
        }

        if (g == 0) {   // lanes 0..7 own dims gl*8..gl*8+7
            float dn = dinv[node];
            int base = node * D + gl * 8;
            if (FINAL == 0) {
                float s2 = dn * dn;
                __half2 h[4];
                h[0] = __floats2half2_rn(acc0 * s2, acc1 * s2);
                h[1] = __floats2half2_rn(acc2 * s2, acc3 * s2);
                h[2] = __floats2half2_rn(acc4 * s2, acc5 * s2);
                h[3] = __floats2half2_rn(acc6 * s2, acc7 * s2);
                *(uint4*)(y_out + base) = *(const uint4*)h;
            } else {
                float rs = rsq[node];
                uint4 v1 = *(const uint4*)(y1 + base);
                uint4 v2 = *(const uint4*)(y2 + base);
                const __half2* h1 = (const __half2*)&v1;
                const __half2* h2 = (const __half2*)&v2;
                fx4 ea = __builtin_nontemporal_load((const fx4*)(emb + base));
                fx4 eb = __builtin_nontemporal_load((const fx4*)(emb + base + 4));
                float2 a0 = __half22float2(h1[0]), b0 = __half22float2(h2[0]);
                float2 a1 = __half22float2(h1[1]), b1 = __half22float2(h2[1]);
                float2 a2 = __half22float2(h1[2]), b2 = __half22float2(h2[2]);
                float2 a3 = __half22float2(h1[3]), b3 = __half22float2(h2[3]);
                fx4 o0, o1;
                o0.x = 0.25f * (ea.x + rs * (a0.x + b0.x) + dn * acc0);
                o0.y = 0.25f * (ea.y + rs * (a0.y + b0.y) + dn * acc1);
                o0.z = 0.25f * (ea.z + rs * (a1.x + b1.x) + dn * acc2);
                o0.w = 0.25f * (ea.w + rs * (a1.y + b1.y) + dn * acc3);
                o1.x = 0.25f * (eb.x + rs * (a2.x + b2.x) + dn * acc4);
                o1.y = 0.25f * (eb.y + rs * (a2.y + b2.y) + dn * acc5);
                o1.z = 0.25f * (eb.z + rs * (a3.x + b3.x) + dn * acc6);
                o1.w = 0.25f * (eb.w + rs * (a3.y + b3.y) + dn * acc7);
                __builtin_nontemporal_store(o0, (fx4*)(out + base));
                __builtin_nontemporal_store(o1, (fx4*)(out + base + 4));
            }
        }
    }
}

extern "C" void kernel_launch(void* const* d_in, const int* in_sizes, int n_in,
                              void* d_out, int out_size, void* d_ws, size_t ws_size,
                              hipStream_t stream) {
    const int*   ei  = (const int*)d_in[0];     // (2, E) int32, row-major
    const float* emb = (const float*)d_in[1];   // (N, D) fp32
    const int* src = ei;
    const int* dst = ei + N_EDGES;
    float* out = (float*)d_out;

    // workspace layout (int units; section starts kept 16B-aligned)
    int* base = (int*)d_ws;
    int* bhist      = base + 0;          // 196
    int* bucketoff  = base + 196;        // 197
    int* bnext      = base + 396;        // 196 -> 592
    int* rowptr     = base + 592;        // 50001 -> pad to 50596
    unsigned int*   tmp     = (unsigned int*)(base + 50596);      // 800000
    unsigned short* csr_src = (unsigned short*)(base + 850596);   // 800000 ushort -> 400000 ints
    float* dinv = (float*)(base + 1250596);   // 50000
    float* rsq  = (float*)(base + 1300596);   // 50000 -> ends 1350596
    __half* y0  = (__half*)(base + 1350596);              // N*D fp16 = 1.6M ints
    __half* y1  = y0 + (size_t)N_NODES * D;
    __half* y2  = y1 + (size_t)N_NODES * D;

    zero_bhist<<<1, 256, 0, stream>>>(bhist);
    bucket_hist<<<512, 256, 0, stream>>>(dst, bhist);
    bucket_scan<<<1, 256, 0, stream>>>(bhist, bucketoff, bnext, rowptr);
    pass_a<<<PA_BLOCKS, 256, 0, stream>>>(src, dst, bnext, tmp);
    pass_b<<<NBUCK, 256, 0, stream>>>(tmp, bucketoff, rowptr, dinv, rsq, csr_src,
                                      emb, y0);

    // y1 = A_s y0
    pull_kernel<0><<<PULL_GRID, 256, 0, stream>>>(rowptr, csr_src, dinv, y0, y1,
                                                  nullptr, nullptr, nullptr, nullptr, nullptr);
    // y2 = A_s y1
    pull_kernel<0><<<PULL_GRID, 256, 0, stream>>>(rowptr, csr_src, dinv, y1, y2,
                                                  nullptr, nullptr, nullptr, nullptr, nullptr);
    // out = 0.25*(emb + rsq*(y1+y2) + dinv*sum(y2))
    pull_kernel<1><<<PULL_GRID, 256, 0, stream>>>(rowptr, csr_src, dinv, y2, nullptr,
                                                  rsq, y1, y2, emb, out);
}

// Round 15
// 124.465 us; speedup vs baseline: 1.0355x; 1.0355x over previous
//
#include <hip/hip_runtime.h>
#include <hip/hip_fp16.h>

#define N_NODES 50000
#define N_EDGES 800000
#define D 64
#define NBUCK 196                 // ceil(N_NODES / 256)
#define BUCK_SHIFT 8
#define HIST_BLOCKS 512
#define PA_CHUNK 2048
#define PA_BLOCKS ((N_EDGES + PA_CHUNK - 1) / PA_CHUNK)   // 391
#define PB_CAP 8192               // Poisson(4082) never reaches this; fallback kept anyway
#define PULL_GRID 2048            // 8 blocks/CU, grid-stride over nodes

__device__ __forceinline__ __half2 shfl_xor_h2(__half2 v, int off) {
    int i; __builtin_memcpy(&i, &v, 4);
    i = __shfl_xor(i, off, 64);
    __half2 r; __builtin_memcpy(&r, &i, 4);
    return r;
}

// ---- coarse histogram: per-block PRIVATE rows (no global zeroing needed) ---
__global__ __launch_bounds__(256) void bucket_hist(const int* __restrict__ dst,
                                                   int* __restrict__ phist) {
    __shared__ int h[NBUCK];
    for (int i = threadIdx.x; i < NBUCK; i += 256) h[i] = 0;
    __syncthreads();
    int stride = gridDim.x * 256;
    for (int e = blockIdx.x * 256 + threadIdx.x; e < N_EDGES; e += stride)
        atomicAdd(&h[dst[e] >> BUCK_SHIFT], 1);
    __syncthreads();
    for (int i = threadIdx.x; i < NBUCK; i += 256)
        phist[blockIdx.x * NBUCK + i] = h[i];    // full overwrite -> deterministic
}

// ---- 1-block: reduce 512 private rows, then exclusive scan -----------------
__global__ __launch_bounds__(256) void bucket_scan(const int* __restrict__ phist,
                                                   int* __restrict__ bucketoff,
                                                   int* __restrict__ bnext,
                                                   int* __restrict__ rowptr) {
    __shared__ int lds[256];
    int t = threadIdx.x;
    int v = 0;
    if (t < NBUCK)
        for (int r = 0; r < HIST_BLOCKS; ++r) v += phist[r * NBUCK + t];
    lds[t] = v;
    __syncthreads();
    for (int off = 1; off < 256; off <<= 1) {
        int u = (t >= off) ? lds[t - off] : 0;
        __syncthreads();
        lds[t] += u;
        __syncthreads();
    }
    if (t < NBUCK) { bucketoff[t] = lds[t] - v; bnext[t] = lds[t] - v; }
    if (t == 0)    { bucketoff[NBUCK] = N_EDGES; rowptr[N_NODES] = N_EDGES; }
}

// ---- pass A: bin edges by dst>>8 into tmp regions (block-privatized) -------
__global__ __launch_bounds__(256) void pass_a(const int* __restrict__ src,
                                              const int* __restrict__ dst,
                                              int* __restrict__ bnext,
                                              unsigned int* __restrict__ tmp) {
    __shared__ int cnt[NBUCK], loc[NBUCK], cur[NBUCK], gbase[NBUCK];
    __shared__ int s[256];
    __shared__ unsigned int stage[PA_CHUNK];
    __shared__ unsigned char sb[PA_CHUNK];
    int t = threadIdx.x;
    int base = blockIdx.x * PA_CHUNK;
    int len = N_EDGES - base; if (len > PA_CHUNK) len = PA_CHUNK;

    for (int i = t; i < NBUCK; i += 256) cnt[i] = 0;
    __syncthreads();
    for (int j = t; j < len; j += 256)
        atomicAdd(&cnt[dst[base + j] >> BUCK_SHIFT], 1);
    __syncthreads();
    int v = (t < NBUCK) ? cnt[t] : 0;
    s[t] = v;
    __syncthreads();
    for (int off = 1; off < 256; off <<= 1) {
        int u = (t >= off) ? s[t - off] : 0;
        __syncthreads();
        s[t] += u;
        __syncthreads();
    }
    if (t < NBUCK) {
        loc[t] = s[t] - v;
        cur[t] = s[t] - v;
        gbase[t] = v ? atomicAdd(&bnext[t], v) : 0;
    }
    __syncthreads();
    for (int j = t; j < len; j += 256) {
        int d = dst[base + j], s0 = src[base + j];
        int b = d >> BUCK_SHIFT;
        int r = atomicAdd(&cur[b], 1);
        stage[r] = ((unsigned)d << 16) | (unsigned)s0;
        sb[r] = (unsigned char)b;
    }
    __syncthreads();
    for (int j = t; j < len; j += 256) {
        int b = sb[j];
        tmp[gbase[b] + (j - loc[b])] = stage[j];
    }
}

// ---- pass B: per-bucket counting sort -> csr_src, rowptr, dinv, rsq; also
// writes y0 rows for its 256-node range (fused scale) ------------------------
__global__ __launch_bounds__(256) void pass_b(const unsigned int* __restrict__ tmp,
                                              const int* __restrict__ bucketoff,
                                              int* __restrict__ rowptr,
                                              float* __restrict__ dinv,
                                              float* __restrict__ rsq,
                                              unsigned short* __restrict__ csr_src,
                                              const float* __restrict__ emb,
                                              __half* __restrict__ y0) {
    __shared__ int hist[256], ptr[256], cur[256];
    __shared__ float sdinv[256];
    __shared__ unsigned int in[PB_CAP];
    __shared__ unsigned short outs[PB_CAP];
    int b = blockIdx.x, t = threadIdx.x;
    int base = bucketoff[b], end = bucketoff[b + 1];
    int k = end - base;
    int node0 = b << BUCK_SHIFT;
    int nloc = N_NODES - node0; if (nloc > 256) nloc = 256;

    hist[t] = 0;
    __syncthreads();
    bool fits = (k <= PB_CAP);
    for (int j = t; j < k; j += 256) {
        unsigned int w = tmp[base + j];
        if (fits) in[j] = w;
        atomicAdd(&hist[(w >> 16) & 255], 1);
    }
    __syncthreads();
    int v = hist[t];
    ptr[t] = v;
    __syncthreads();
    for (int off = 1; off < 256; off <<= 1) {
        int u = (t >= off) ? ptr[t - off] : 0;
        __syncthreads();
        ptr[t] += u;
        __syncthreads();
    }
    int excl = ptr[t] - v;
    cur[t] = excl;
    if (t < nloc) {
        float dn = v > 0 ? rsqrtf((float)v) : 0.0f;
        rowptr[node0 + t] = base + excl;
        dinv[node0 + t] = dn;
        rsq[node0 + t]  = sqrtf((float)v);
        sdinv[t] = dn;
    }
    __syncthreads();
    if (fits) {
        for (int j = t; j < k; j += 256) {
            unsigned int w = in[j];
            int r = atomicAdd(&cur[(w >> 16) & 255], 1);
            outs[r] = (unsigned short)(w & 0xFFFF);
        }
        __syncthreads();
        for (int j = t; j < k; j += 256) csr_src[base + j] = outs[j];
    } else {
        for (int j = t; j < k; j += 256) {
            unsigned int w = tmp[base + j];
            int r = atomicAdd(&cur[(w >> 16) & 255], 1);
            csr_src[base + r] = (unsigned short)(w & 0xFFFF);
        }
    }

    // fused scale: y0[n,:] = dinv[n] * emb[n,:] for this bucket's nodes
    int nv = nloc * 8;                    // uint4 stores (8 fp16 each)
    for (int q = t; q < nv; q += 256) {
        int n   = q >> 3;
        int off = (q & 7) * 8;
        float s = sdinv[n];
        const float* ep = emb + (size_t)(node0 + n) * D + off;
        float4 a = *(const float4*)ep;
        float4 bb = *(const float4*)(ep + 4);
        __half2 h[4];
        h[0] = __floats2half2_rn(a.x * s, a.y * s);
        h[1] = __floats2half2_rn(a.z * s, a.w * s);
        h[2] = __floats2half2_rn(bb.x * s, bb.y * s);
        h[3] = __floats2half2_rn(bb.z * s, bb.w * s);
        *(uint4*)(y0 + (size_t)(node0 + n) * D + off) = *(const uint4*)h;
    }
}

// ---- pull: grid-stride, one wave per dst node; 8 groups x 8 dims -----------
// One VMEM instr fetches 8 full 128B rows. Cross-group reduce done on packed
// half2 (12 shfl + 12 pk-adds instead of 24+24).
// FINAL=0: y_out = dinv^2 * acc.  FINAL=1: out = 0.25*(emb + rsq*(y1+y2) + dinv*acc)
template <int FINAL>
__global__ __launch_bounds__(256) void pull_kernel(
        const int* __restrict__ rowptr, const unsigned short* __restrict__ csr_src,
        const float* __restrict__ dinv, const __half* __restrict__ y,
        __half* __restrict__ y_out,
        const float* __restrict__ rsq, const __half* __restrict__ y1,
        const __half* __restrict__ y2, const float* __restrict__ emb,
        float* __restrict__ out) {
    int lane = threadIdx.x & 63;
    int g  = lane >> 3;     // group 0..7 (edge slot within chunk)
    int gl = lane & 7;      // lane in group (dim block)
    int node0 = blockIdx.x * 4 + (threadIdx.x >> 6);

    for (int node = node0; node < N_NODES; node += PULL_GRID * 4) {
        int beg = rowptr[node];
        int end = rowptr[node + 1];

        float acc0 = 0.f, acc1 = 0.f, acc2 = 0.f, acc3 = 0.f;
        float acc4 = 0.f, acc5 = 0.f, acc6 = 0.f, acc7 = 0.f;

        for (int e0 = beg; e0 < end; e0 += 64) {
            int kk = end - e0; if (kk > 64) kk = 64;
            int idxv = (e0 + lane < end) ? (int)csr_src[e0 + lane] : 0;
            int nch = (kk + 7) >> 3;
            for (int i = 0; i < nch; ++i) {
                int pos = 8 * i + g;
                int s = __shfl(idxv, pos, 64);
                if (pos < kk) {
                    const uint4* p = (const uint4*)(y + (size_t)s * D + gl * 8);
                    uint4 v = *p;
                    const __half2* h = (const __half2*)&v;
                    float2 f0 = __half22float2(h[0]);
                    float2 f1 = __half22float2(h[1]);
                    float2 f2 = __half22float2(h[2]);
                    float2 f3 = __half22float2(h[3]);
                    acc0 += f0.x; acc1 += f0.y; acc2 += f1.x; acc3 += f1.y;
                    acc4 += f2.x; acc5 += f2.y; acc6 += f3.x; acc7 += f3.y;
                }
            }
        }

        // pack partials to half2, reduce across the 8 groups (offsets 8/16/32)
        __half2 p0 = __floats2half2_rn(acc0, acc1);
        __half2 p1 = __floats2half2_rn(acc2, acc3);
        __half2 p2 = __floats2half2_rn(acc4, acc5);
        __half2 p3 = __floats2half2_rn(acc6, acc7);
        #pragma unroll
        for (int off = 8; off < 64; off <<= 1) {
            p0 = __hadd2(p0, shfl_xor_h2(p0, off));
            p1 = __hadd2(p1, shfl_xor_h2(p1, off));
            p2 = __hadd2(p2, shfl_xor_h2(p2, off));
            p3 = __hadd2(p3, shfl_xor_h2(p3, off));
        }

        if (g == 0) {   // lanes 0..7 own dims gl*8..gl*8+7
            float dn = dinv[node];
            int base = node * D + gl * 8;
            float2 s0 = __half22float2(p0);
            float2 s1 = __half22float2(p1);
            float2 s2 = __half22float2(p2);
            float2 s3 = __half22float2(p3);
            if (FINAL == 0) {
                float q = dn * dn;
                __half2 h[4];
                h[0] = __floats2half2_rn(s0.x * q, s0.y * q);
                h[1] = __floats2half2_rn(s1.x * q, s1.y * q);
                h[2] = __floats2half2_rn(s2.x * q, s2.y * q);
                h[3] = __floats2half2_rn(s3.x * q, s3.y * q);
                *(uint4*)(y_out + base) = *(const uint4*)h;
            } else {
                float rs = rsq[node];
                uint4 v1 = *(const uint4*)(y1 + base);
                uint4 v2 = *(const uint4*)(y2 + base);
                const __half2* h1 = (const __half2*)&v1;
                const __half2* h2 = (const __half2*)&v2;
                float4 ea = *(const float4*)(emb + base);
                float4 eb = *(const float4*)(emb + base + 4);
                float2 a0 = __half22float2(h1[0]), b0 = __half22float2(h2[0]);
                float2 a1 = __half22float2(h1[1]), b1 = __half22float2(h2[1]);
                float2 a2 = __half22float2(h1[2]), b2 = __half22float2(h2[2]);
                float2 a3 = __half22float2(h1[3]), b3 = __half22float2(h2[3]);
                float4 o0, o1;
                o0.x = 0.25f * (ea.x + rs * (a0.x + b0.x) + dn * s0.x);
                o0.y = 0.25f * (ea.y + rs * (a0.y + b0.y) + dn * s0.y);
                o0.z = 0.25f * (ea.z + rs * (a1.x + b1.x) + dn * s1.x);
                o0.w = 0.25f * (ea.w + rs * (a1.y + b1.y) + dn * s1.y);
                o1.x = 0.25f * (eb.x + rs * (a2.x + b2.x) + dn * s2.x);
                o1.y = 0.25f * (eb.y + rs * (a2.y + b2.y) + dn * s2.y);
                o1.z = 0.25f * (eb.z + rs * (a3.x + b3.x) + dn * s3.x);
                o1.w = 0.25f * (eb.w + rs * (a3.y + b3.y) + dn * s3.y);
                *(float4*)(out + base)     = o0;
                *(float4*)(out + base + 4) = o1;
            }
        }
    }
}

extern "C" void kernel_launch(void* const* d_in, const int* in_sizes, int n_in,
                              void* d_out, int out_size, void* d_ws, size_t ws_size,
                              hipStream_t stream) {
    const int*   ei  = (const int*)d_in[0];     // (2, E) int32, row-major
    const float* emb = (const float*)d_in[1];   // (N, D) fp32
    const int* src = ei;
    const int* dst = ei + N_EDGES;
    float* out = (float*)d_out;

    // workspace layout (int units; section starts kept 16B-aligned)
    int* base = (int*)d_ws;
    int* phist      = base + 0;            // 512*196 = 100352 -> pad to 100352
    int* bucketoff  = base + 100352;       // 197
    int* bnext      = base + 100552;       // 196 -> ends 100748, pad 100752
    int* rowptr     = base + 100752;       // 50001 -> pad to 150756
    unsigned int*   tmp     = (unsigned int*)(base + 150756);      // 800000
    unsigned short* csr_src = (unsigned short*)(base + 950756);    // 800000 ushort
    float* dinv = (float*)(base + 1350756);   // 50000
    float* rsq  = (float*)(base + 1400756);   // 50000 -> ends 1450756
    __half* y0  = (__half*)(base + 1450756);              // N*D fp16 = 1.6M ints
    __half* y1  = y0 + (size_t)N_NODES * D;
    __half* y2  = y1 + (size_t)N_NODES * D;

    bucket_hist<<<HIST_BLOCKS, 256, 0, stream>>>(dst, phist);
    bucket_scan<<<1, 256, 0, stream>>>(phist, bucketoff, bnext, rowptr);
    pass_a<<<PA_BLOCKS, 256, 0, stream>>>(src, dst, bnext, tmp);
    pass_b<<<NBUCK, 256, 0, stream>>>(tmp, bucketoff, rowptr, dinv, rsq, csr_src,
                                      emb, y0);

    // y1 = A_s y0
    pull_kernel<0><<<PULL_GRID, 256, 0, stream>>>(rowptr, csr_src, dinv, y0, y1,
                                                  nullptr, nullptr, nullptr, nullptr, nullptr);
    // y2 = A_s y1
    pull_kernel<0><<<PULL_GRID, 256, 0, stream>>>(rowptr, csr_src, dinv, y1, y2,
                                                  nullptr, nullptr, nullptr, nullptr, nullptr);
    // out = 0.25*(emb + rsq*(y1+y2) + dinv*sum(y2))
    pull_kernel<1><<<PULL_GRID, 256, 0, stream>>>(rowptr, csr_src, dinv, y2, nullptr,
                                                  rsq, y1, y2, emb, out);
}

// Round 16
// 123.238 us; speedup vs baseline: 1.0458x; 1.0100x over previous
//
#include <hip/hip_runtime.h>
#include <hip/hip_fp16.h>

#define N_NODES 50000
#define NHALF   25000
#define N_EDGES 800000
#define D 64
#define NBUCK 196                 // ceil(N_NODES / 256)
#define BUCK_SHIFT 8
#define HIST_BLOCKS 512
#define PA_CHUNK 2048
#define PA_BLOCKS ((N_EDGES + PA_CHUNK - 1) / PA_CHUNK)   // 391
#define PB_CAP 8192               // Poisson(4082) never reaches this; fallback kept anyway
#define PULL_GRID 2048            // 8 blocks/CU, grid-stride over node pairs

__device__ __forceinline__ __half2 shfl_xor_h2(__half2 v, int off) {
    int i; __builtin_memcpy(&i, &v, 4);
    i = __shfl_xor(i, off, 64);
    __half2 r; __builtin_memcpy(&r, &i, 4);
    return r;
}

// ---- coarse histogram: per-block PRIVATE rows (no global zeroing needed) ---
__global__ __launch_bounds__(256) void bucket_hist(const int* __restrict__ dst,
                                                   int* __restrict__ phist) {
    __shared__ int h[NBUCK];
    for (int i = threadIdx.x; i < NBUCK; i += 256) h[i] = 0;
    __syncthreads();
    int stride = gridDim.x * 256;
    for (int e = blockIdx.x * 256 + threadIdx.x; e < N_EDGES; e += stride)
        atomicAdd(&h[dst[e] >> BUCK_SHIFT], 1);
    __syncthreads();
    for (int i = threadIdx.x; i < NBUCK; i += 256)
        phist[blockIdx.x * NBUCK + i] = h[i];    // full overwrite -> deterministic
}

// ---- 1-block: reduce 512 private rows, then exclusive scan -----------------
__global__ __launch_bounds__(256) void bucket_scan(const int* __restrict__ phist,
                                                   int* __restrict__ bucketoff,
                                                   int* __restrict__ bnext,
                                                   int* __restrict__ rowptr) {
    __shared__ int lds[256];
    int t = threadIdx.x;
    int v = 0;
    if (t < NBUCK)
        for (int r = 0; r < HIST_BLOCKS; ++r) v += phist[r * NBUCK + t];
    lds[t] = v;
    __syncthreads();
    for (int off = 1; off < 256; off <<= 1) {
        int u = (t >= off) ? lds[t - off] : 0;
        __syncthreads();
        lds[t] += u;
        __syncthreads();
    }
    if (t < NBUCK) { bucketoff[t] = lds[t] - v; bnext[t] = lds[t] - v; }
    if (t == 0)    { bucketoff[NBUCK] = N_EDGES; rowptr[N_NODES] = N_EDGES; }
}

// ---- pass A: bin edges by dst>>8 into tmp regions (block-privatized) -------
__global__ __launch_bounds__(256) void pass_a(const int* __restrict__ src,
                                              const int* __restrict__ dst,
                                              int* __restrict__ bnext,
                                              unsigned int* __restrict__ tmp) {
    __shared__ int cnt[NBUCK], loc[NBUCK], cur[NBUCK], gbase[NBUCK];
    __shared__ int s[256];
    __shared__ unsigned int stage[PA_CHUNK];
    __shared__ unsigned char sb[PA_CHUNK];
    int t = threadIdx.x;
    int base = blockIdx.x * PA_CHUNK;
    int len = N_EDGES - base; if (len > PA_CHUNK) len = PA_CHUNK;

    for (int i = t; i < NBUCK; i += 256) cnt[i] = 0;
    __syncthreads();
    for (int j = t; j < len; j += 256)
        atomicAdd(&cnt[dst[base + j] >> BUCK_SHIFT], 1);
    __syncthreads();
    int v = (t < NBUCK) ? cnt[t] : 0;
    s[t] = v;
    __syncthreads();
    for (int off = 1; off < 256; off <<= 1) {
        int u = (t >= off) ? s[t - off] : 0;
        __syncthreads();
        s[t] += u;
        __syncthreads();
    }
    if (t < NBUCK) {
        loc[t] = s[t] - v;
        cur[t] = s[t] - v;
        gbase[t] = v ? atomicAdd(&bnext[t], v) : 0;
    }
    __syncthreads();
    for (int j = t; j < len; j += 256) {
        int d = dst[base + j], s0 = src[base + j];
        int b = d >> BUCK_SHIFT;
        int r = atomicAdd(&cur[b], 1);
        stage[r] = ((unsigned)d << 16) | (unsigned)s0;
        sb[r] = (unsigned char)b;
    }
    __syncthreads();
    for (int j = t; j < len; j += 256) {
        int b = sb[j];
        tmp[gbase[b] + (j - loc[b])] = stage[j];
    }
}

// ---- pass B: per-bucket counting sort -> csr_src, rowptr, dinv, rsq; also
// writes y0 rows for its 256-node range (fused scale) ------------------------
__global__ __launch_bounds__(256) void pass_b(const unsigned int* __restrict__ tmp,
                                              const int* __restrict__ bucketoff,
                                              int* __restrict__ rowptr,
                                              float* __restrict__ dinv,
                                              float* __restrict__ rsq,
                                              unsigned short* __restrict__ csr_src,
                                              const float* __restrict__ emb,
                                              __half* __restrict__ y0) {
    __shared__ int hist[256], ptr[256], cur[256];
    __shared__ float sdinv[256];
    __shared__ unsigned int in[PB_CAP];
    __shared__ unsigned short outs[PB_CAP];
    int b = blockIdx.x, t = threadIdx.x;
    int base = bucketoff[b], end = bucketoff[b + 1];
    int k = end - base;
    int node0 = b << BUCK_SHIFT;
    int nloc = N_NODES - node0; if (nloc > 256) nloc = 256;

    hist[t] = 0;
    __syncthreads();
    bool fits = (k <= PB_CAP);
    for (int j = t; j < k; j += 256) {
        unsigned int w = tmp[base + j];
        if (fits) in[j] = w;
        atomicAdd(&hist[(w >> 16) & 255], 1);
    }
    __syncthreads();
    int v = hist[t];
    ptr[t] = v;
    __syncthreads();
    for (int off = 1; off < 256; off <<= 1) {
        int u = (t >= off) ? ptr[t - off] : 0;
        __syncthreads();
        ptr[t] += u;
        __syncthreads();
    }
    int excl = ptr[t] - v;
    cur[t] = excl;
    if (t < nloc) {
        float dn = v > 0 ? rsqrtf((float)v) : 0.0f;
        rowptr[node0 + t] = base + excl;
        dinv[node0 + t] = dn;
        rsq[node0 + t]  = sqrtf((float)v);
        sdinv[t] = dn;
    }
    __syncthreads();
    if (fits) {
        for (int j = t; j < k; j += 256) {
            unsigned int w = in[j];
            int r = atomicAdd(&cur[(w >> 16) & 255], 1);
            outs[r] = (unsigned short)(w & 0xFFFF);
        }
        __syncthreads();
        for (int j = t; j < k; j += 256) csr_src[base + j] = outs[j];
    } else {
        for (int j = t; j < k; j += 256) {
            unsigned int w = tmp[base + j];
            int r = atomicAdd(&cur[(w >> 16) & 255], 1);
            csr_src[base + r] = (unsigned short)(w & 0xFFFF);
        }
    }

    // fused scale: y0[n,:] = dinv[n] * emb[n,:] for this bucket's nodes
    int nv = nloc * 8;                    // uint4 stores (8 fp16 each)
    for (int q = t; q < nv; q += 256) {
        int n   = q >> 3;
        int off = (q & 7) * 8;
        float s = sdinv[n];
        const float* ep = emb + (size_t)(node0 + n) * D + off;
        float4 a = *(const float4*)ep;
        float4 bb = *(const float4*)(ep + 4);
        __half2 h[4];
        h[0] = __floats2half2_rn(a.x * s, a.y * s);
        h[1] = __floats2half2_rn(a.z * s, a.w * s);
        h[2] = __floats2half2_rn(bb.x * s, bb.y * s);
        h[3] = __floats2half2_rn(bb.z * s, bb.w * s);
        *(uint4*)(y0 + (size_t)(node0 + n) * D + off) = *(const uint4*)h;
    }
}

// epilogue for one node (called by g==0 lanes; gl in 0..7 owns dims gl*8..+7)
template <int FINAL>
__device__ __forceinline__ void pull_epi(
        int node, int gl, __half2 p0, __half2 p1, __half2 p2, __half2 p3,
        const float* __restrict__ dinv, const float* __restrict__ rsq,
        const __half* __restrict__ y1, const __half* __restrict__ y2,
        const float* __restrict__ emb, __half* __restrict__ y_out,
        float* __restrict__ out) {
    float dn = dinv[node];
    int base = node * D + gl * 8;
    float2 s0 = __half22float2(p0);
    float2 s1 = __half22float2(p1);
    float2 s2 = __half22float2(p2);
    float2 s3 = __half22float2(p3);
    if (FINAL == 0) {
        float q = dn * dn;
        __half2 h[4];
        h[0] = __floats2half2_rn(s0.x * q, s0.y * q);
        h[1] = __floats2half2_rn(s1.x * q, s1.y * q);
        h[2] = __floats2half2_rn(s2.x * q, s2.y * q);
        h[3] = __floats2half2_rn(s3.x * q, s3.y * q);
        *(uint4*)(y_out + base) = *(const uint4*)h;
    } else {
        float rs = rsq[node];
        uint4 v1 = *(const uint4*)(y1 + base);
        uint4 v2 = *(const uint4*)(y2 + base);
        const __half2* h1 = (const __half2*)&v1;
        const __half2* h2 = (const __half2*)&v2;
        float4 ea = *(const float4*)(emb + base);
        float4 eb = *(const float4*)(emb + base + 4);
        float2 a0 = __half22float2(h1[0]), b0 = __half22float2(h2[0]);
        float2 a1 = __half22float2(h1[1]), b1 = __half22float2(h2[1]);
        float2 a2 = __half22float2(h1[2]), b2 = __half22float2(h2[2]);
        float2 a3 = __half22float2(h1[3]), b3 = __half22float2(h2[3]);
        float4 o0, o1;
        o0.x = 0.25f * (ea.x + rs * (a0.x + b0.x) + dn * s0.x);
        o0.y = 0.25f * (ea.y + rs * (a0.y + b0.y) + dn * s0.y);
        o0.z = 0.25f * (ea.z + rs * (a1.x + b1.x) + dn * s1.x);
        o0.w = 0.25f * (ea.w + rs * (a1.y + b1.y) + dn * s1.y);
        o1.x = 0.25f * (eb.x + rs * (a2.x + b2.x) + dn * s2.x);
        o1.y = 0.25f * (eb.y + rs * (a2.y + b2.y) + dn * s2.y);
        o1.z = 0.25f * (eb.z + rs * (a3.x + b3.x) + dn * s3.x);
        o1.w = 0.25f * (eb.w + rs * (a3.y + b3.y) + dn * s3.y);
        *(float4*)(out + base)     = o0;
        *(float4*)(out + base + 4) = o1;
    }
}

// ---- pull: grid-stride over NODE PAIRS (n, n+25000); 2 independent VMEM
// chains per wave iteration for 2x MLP. 8 groups x 8 dims; one gather instr
// fetches 8 full 128B rows. Zero-filled masked loads -> branch-free adds.
template <int FINAL>
__global__ __launch_bounds__(256) void pull_kernel(
        const int* __restrict__ rowptr, const unsigned short* __restrict__ csr_src,
        const float* __restrict__ dinv, const __half* __restrict__ y,
        __half* __restrict__ y_out,
        const float* __restrict__ rsq, const __half* __restrict__ y1,
        const __half* __restrict__ y2, const float* __restrict__ emb,
        float* __restrict__ out) {
    int lane = threadIdx.x & 63;
    int g  = lane >> 3;     // group 0..7 (edge slot within chunk)
    int gl = lane & 7;      // lane in group (dim block)
    int w0 = blockIdx.x * 4 + (threadIdx.x >> 6);

    for (int nA = w0; nA < NHALF; nA += PULL_GRID * 4) {
        int nB = nA + NHALF;
        int begA = rowptr[nA], endA = rowptr[nA + 1];
        int begB = rowptr[nB], endB = rowptr[nB + 1];

        float aA0=0.f,aA1=0.f,aA2=0.f,aA3=0.f,aA4=0.f,aA5=0.f,aA6=0.f,aA7=0.f;
        float aB0=0.f,aB1=0.f,aB2=0.f,aB3=0.f,aB4=0.f,aB5=0.f,aB6=0.f,aB7=0.f;

        // first (almost always only) chunk of each node, interleaved
        int idxvA = (begA + lane < endA) ? (int)csr_src[begA + lane] : 0;
        int idxvB = (begB + lane < endB) ? (int)csr_src[begB + lane] : 0;
        int kkA = endA - begA; if (kkA > 64) kkA = 64;
        int kkB = endB - begB; if (kkB > 64) kkB = 64;
        int nchA = (kkA + 7) >> 3, nchB = (kkB + 7) >> 3;
        int nch = nchA > nchB ? nchA : nchB;
        for (int i = 0; i < nch; ++i) {
            int pos = 8 * i + g;
            int sA = __shfl(idxvA, pos, 64);
            int sB = __shfl(idxvB, pos, 64);
            uint4 vA = {0u,0u,0u,0u}, vB = {0u,0u,0u,0u};
            if (pos < kkA) vA = *(const uint4*)(y + (size_t)sA * D + gl * 8);
            if (pos < kkB) vB = *(const uint4*)(y + (size_t)sB * D + gl * 8);
            const __half2* hA = (const __half2*)&vA;
            const __half2* hB = (const __half2*)&vB;
            float2 f0 = __half22float2(hA[0]), f1 = __half22float2(hA[1]);
            float2 f2 = __half22float2(hA[2]), f3 = __half22float2(hA[3]);
            aA0 += f0.x; aA1 += f0.y; aA2 += f1.x; aA3 += f1.y;
            aA4 += f2.x; aA5 += f2.y; aA6 += f3.x; aA7 += f3.y;
            float2 g0 = __half22float2(hB[0]), g1 = __half22float2(hB[1]);
            float2 g2 = __half22float2(hB[2]), g3 = __half22float2(hB[3]);
            aB0 += g0.x; aB1 += g0.y; aB2 += g1.x; aB3 += g1.y;
            aB4 += g2.x; aB5 += g2.y; aB6 += g3.x; aB7 += g3.y;
        }
        // rare tails (degree > 64)
        for (int e0 = begA + 64; e0 < endA; e0 += 64) {
            int kk = endA - e0; if (kk > 64) kk = 64;
            int idxv = (e0 + lane < endA) ? (int)csr_src[e0 + lane] : 0;
            int nch2 = (kk + 7) >> 3;
            for (int i = 0; i < nch2; ++i) {
                int pos = 8 * i + g;
                int s = __shfl(idxv, pos, 64);
                uint4 v = {0u,0u,0u,0u};
                if (pos < kk) v = *(const uint4*)(y + (size_t)s * D + gl * 8);
                const __half2* h = (const __half2*)&v;
                float2 f0 = __half22float2(h[0]), f1 = __half22float2(h[1]);
                float2 f2 = __half22float2(h[2]), f3 = __half22float2(h[3]);
                aA0 += f0.x; aA1 += f0.y; aA2 += f1.x; aA3 += f1.y;
                aA4 += f2.x; aA5 += f2.y; aA6 += f3.x; aA7 += f3.y;
            }
        }
        for (int e0 = begB + 64; e0 < endB; e0 += 64) {
            int kk = endB - e0; if (kk > 64) kk = 64;
            int idxv = (e0 + lane < endB) ? (int)csr_src[e0 + lane] : 0;
            int nch2 = (kk + 7) >> 3;
            for (int i = 0; i < nch2; ++i) {
                int pos = 8 * i + g;
                int s = __shfl(idxv, pos, 64);
                uint4 v = {0u,0u,0u,0u};
                if (pos < kk) v = *(const uint4*)(y + (size_t)s * D + gl * 8);
                const __half2* h = (const __half2*)&v;
                float2 f0 = __half22float2(h[0]), f1 = __half22float2(h[1]);
                float2 f2 = __half22float2(h[2]), f3 = __half22float2(h[3]);
                aB0 += f0.x; aB1 += f0.y; aB2 += f1.x; aB3 += f1.y;
                aB4 += f2.x; aB5 += f2.y; aB6 += f3.x; aB7 += f3.y;
            }
        }

        // pack partials to half2; reduce both nodes across the 8 groups
        __half2 pA0 = __floats2half2_rn(aA0, aA1);
        __half2 pA1 = __floats2half2_rn(aA2, aA3);
        __half2 pA2 = __floats2half2_rn(aA4, aA5);
        __half2 pA3 = __floats2half2_rn(aA6, aA7);
        __half2 pB0 = __floats2half2_rn(aB0, aB1);
        __half2 pB1 = __floats2half2_rn(aB2, aB3);
        __half2 pB2 = __floats2half2_rn(aB4, aB5);
        __half2 pB3 = __floats2half2_rn(aB6, aB7);
        #pragma unroll
        for (int off = 8; off < 64; off <<= 1) {
            pA0 = __hadd2(pA0, shfl_xor_h2(pA0, off));
            pA1 = __hadd2(pA1, shfl_xor_h2(pA1, off));
            pA2 = __hadd2(pA2, shfl_xor_h2(pA2, off));
            pA3 = __hadd2(pA3, shfl_xor_h2(pA3, off));
            pB0 = __hadd2(pB0, shfl_xor_h2(pB0, off));
            pB1 = __hadd2(pB1, shfl_xor_h2(pB1, off));
            pB2 = __hadd2(pB2, shfl_xor_h2(pB2, off));
            pB3 = __hadd2(pB3, shfl_xor_h2(pB3, off));
        }

        if (g == 0) {
            pull_epi<FINAL>(nA, gl, pA0, pA1, pA2, pA3, dinv, rsq, y1, y2, emb, y_out, out);
            pull_epi<FINAL>(nB, gl, pB0, pB1, pB2, pB3, dinv, rsq, y1, y2, emb, y_out, out);
        }
    }
}

extern "C" void kernel_launch(void* const* d_in, const int* in_sizes, int n_in,
                              void* d_out, int out_size, void* d_ws, size_t ws_size,
                              hipStream_t stream) {
    const int*   ei  = (const int*)d_in[0];     // (2, E) int32, row-major
    const float* emb = (const float*)d_in[1];   // (N, D) fp32
    const int* src = ei;
    const int* dst = ei + N_EDGES;
    float* out = (float*)d_out;

    // workspace layout (int units; section starts kept 16B-aligned)
    int* base = (int*)d_ws;
    int* phist      = base + 0;            // 512*196 = 100352
    int* bucketoff  = base + 100352;       // 197
    int* bnext      = base + 100552;       // 196 -> ends 100748, pad 100752
    int* rowptr     = base + 100752;       // 50001 -> pad to 150756
    unsigned int*   tmp     = (unsigned int*)(base + 150756);      // 800000
    unsigned short* csr_src = (unsigned short*)(base + 950756);    // 800000 ushort
    float* dinv = (float*)(base + 1350756);   // 50000
    float* rsq  = (float*)(base + 1400756);   // 50000 -> ends 1450756
    __half* y0  = (__half*)(base + 1450756);              // N*D fp16 = 1.6M ints
    __half* y1  = y0 + (size_t)N_NODES * D;
    __half* y2  = y1 + (size_t)N_NODES * D;

    bucket_hist<<<HIST_BLOCKS, 256, 0, stream>>>(dst, phist);
    bucket_scan<<<1, 256, 0, stream>>>(phist, bucketoff, bnext, rowptr);
    pass_a<<<PA_BLOCKS, 256, 0, stream>>>(src, dst, bnext, tmp);
    pass_b<<<NBUCK, 256, 0, stream>>>(tmp, bucketoff, rowptr, dinv, rsq, csr_src,
                                      emb, y0);

    // y1 = A_s y0
    pull_kernel<0><<<PULL_GRID, 256, 0, stream>>>(rowptr, csr_src, dinv, y0, y1,
                                                  nullptr, nullptr, nullptr, nullptr, nullptr);
    // y2 = A_s y1
    pull_kernel<0><<<PULL_GRID, 256, 0, stream>>>(rowptr, csr_src, dinv, y1, y2,
                                                  nullptr, nullptr, nullptr, nullptr, nullptr);
    // out = 0.25*(emb + rsq*(y1+y2) + dinv*sum(y2))
    pull_kernel<1><<<PULL_GRID, 256, 0, stream>>>(rowptr, csr_src, dinv, y2, nullptr,
                                                  rsq, y1, y2, emb, out);
}